// Round 10
// baseline (574.103 us; speedup 1.0000x reference)
//
#include <hip/hip_runtime.h>
#include <math.h>

// ---- Problem constants (fixed by the reference) ----
constexpr int BATCH = 262144;
constexpr int M_  = 2;
constexpr int N_  = 4;
constexpr int NB_ = 5;
constexpr int NH_ = 8;
constexpr int HD_ = 4;
constexpr int HID_ = 32;
constexpr float D_v    = 50.0f;
constexpr float HZ_v   = 5.0f;
constexpr float DMIN_v = 0.025f;
constexpr float PMAX_v = 1.0f;
constexpr float SCALE_v = 0.5f;                            // 1/sqrt(HD)
constexpr float BMAX_v  = 2.0f * D_v - (N_ - 1) * DMIN_v;  // 99.925

// ---- Packed-weight layout in d_ws (float offsets) ----
// HP  [5][8][32]     : per (layer,head), de-interleaved:
//                      wu_e4 | wu_o4 | wa_e4 | wa_o4 | we4 | av*SCALE 4 | wres0 4 | wres1 4
// W1G [5][2][32][16] : w1 transposed, LN gain folded ([d][br][col][j])
// SGB [5][4][16]     : per d: G_mu | B_mu | G_ma | B_ma (G=sum g*w1, B=sum b*w1+b1)
// W2  [5][2][40]     : w2 row0(16) | row1(16) | b2(2) | pad(6)
// RO  [160]          : rd_w1 rd_b1 rd_w2 rd_b2 rp_w1 rp_b1 rp_w2 rp_b2 pad
constexpr int HP_OFF  = 0;      // 1280
constexpr int W1G_OFF = 1280;   // 5120
constexpr int SGB_OFF = 6400;   // 320
constexpr int W2_OFF  = 6720;   // 400
constexpr int RO_OFF  = 7120;   // 160
constexpr int TOTF    = 7280;

typedef __attribute__((ext_vector_type(2))) float f2;

__device__ __forceinline__ float frcp(float x) { return __builtin_amdgcn_rcpf(x); }
__device__ __forceinline__ f2 sp2(float x) { return (f2){x, x}; }
__device__ __forceinline__ f2 pfma(f2 a, f2 b, f2 c) { return __builtin_elementwise_fma(a, b, c); }
__device__ __forceinline__ f2 pmax2(f2 a, f2 b) { return __builtin_elementwise_max(a, b); }

// ---- forced VOP3P for the dominant w1 matvec only (R8: proven neutral-to-
// positive). Tied accumulator ("+v") => no copy; op_sel broadcast => no v_mov.
__device__ __forceinline__ void pk_fma_wlo(f2& acc, f2 w, f2 x) {
    asm("v_pk_fma_f32 %0, %1, %2, %0 op_sel:[0,0,0] op_sel_hi:[1,0,1]"
        : "+v"(acc) : "s"(w), "v"(x));
}
__device__ __forceinline__ void pk_fma_whi(f2& acc, f2 w, f2 x) {
    asm("v_pk_fma_f32 %0, %1, %2, %0 op_sel:[0,1,0] op_sel_hi:[1,1,1]"
        : "+v"(acc) : "s"(w), "v"(x));
}

// Single dispatch. Every block redundantly writes the full deterministic pack
// to ws (identical values -> benign races; each block depends only on its own
// writes), then threadfence + barrier (vmcnt(0) drain) + s_dcache_inv so the
// wave-uniform s_loads below cannot serve stale scalar-cache lines.
__global__ __launch_bounds__(256) void bgat_fwd(
    const float* __restrict__ users, const float* __restrict__ delta_init,
    const float* __restrict__ power_init,
    const float* __restrict__ Wu, const float* __restrict__ Wa,
    const float* __restrict__ We, const float* __restrict__ av,
    const float* __restrict__ Wres,
    const float* __restrict__ lnu_g, const float* __restrict__ lnu_b,
    const float* __restrict__ lna_g, const float* __restrict__ lna_b,
    const float* __restrict__ mu_w1, const float* __restrict__ mu_b1,
    const float* __restrict__ mu_w2, const float* __restrict__ mu_b2,
    const float* __restrict__ ma_w1, const float* __restrict__ ma_b1,
    const float* __restrict__ ma_w2, const float* __restrict__ ma_b2,
    const float* __restrict__ rd_w1, const float* __restrict__ rd_b1,
    const float* __restrict__ rd_w2, const float* __restrict__ rd_b2,
    const float* __restrict__ rp_w1, const float* __restrict__ rp_b1,
    const float* __restrict__ rp_w2, const float* __restrict__ rp_b2,
    float* ws, float* __restrict__ out)
{
    // ---- per-block redundant pack (global, ~3us, fully parallel) ----
    {
        const int t = threadIdx.x;
        for (int idx = t; idx < 1280; idx += 256) {
            const int d = idx >> 8, r = idx & 255, k = r >> 5, s = r & 31;
            const int dk = d * 8 + k;
            float v;
            if      (s <  4) v = Wu[dk * 8 + 2 * s];
            else if (s <  8) v = Wu[dk * 8 + 2 * (s - 4) + 1];
            else if (s < 12) v = Wa[dk * 8 + 2 * (s - 8)];
            else if (s < 16) v = Wa[dk * 8 + 2 * (s - 12) + 1];
            else if (s < 20) v = We[dk * 4 + (s - 16)];
            else if (s < 24) v = av[dk * 4 + (s - 20)] * SCALE_v;
            else if (s < 28) v = Wres[(d * 32 + k * 4 + (s - 24)) * 2 + 0];
            else             v = Wres[(d * 32 + k * 4 + (s - 28)) * 2 + 1];
            ws[HP_OFF + idx] = v;
        }
        for (int idx = t; idx < 5120; idx += 256) {
            const int d = idx >> 10, r = idx & 1023, br = r >> 9, r2 = r & 511;
            const int col = r2 >> 4, j = r2 & 15;
            const float* w1 = br ? ma_w1 : mu_w1;
            const float* g  = br ? lna_g : lnu_g;
            ws[W1G_OFF + idx] = w1[(d * 16 + j) * 32 + col] * g[d * 32 + col];
        }
        for (int idx = t; idx < 320; idx += 256) {
            const int d = idx >> 6, r = idx & 63, q = r >> 4, j = r & 15;
            const int br = q >> 1, gb = q & 1;
            const float* w1 = (br ? ma_w1 : mu_w1) + (d * 16 + j) * 32;
            const float* gv = (br ? lna_g : lnu_g) + d * 32;
            const float* bv = (br ? lna_b : lnu_b) + d * 32;
            float acc = 0.f;
            if (gb == 0) { for (int i = 0; i < 32; ++i) acc = fmaf(gv[i], w1[i], acc); }
            else {
                for (int i = 0; i < 32; ++i) acc = fmaf(bv[i], w1[i], acc);
                acc += (br ? ma_b1 : mu_b1)[d * 16 + j];
            }
            ws[SGB_OFF + idx] = acc;
        }
        for (int idx = t; idx < 400; idx += 256) {
            const int d = idx / 80, r = idx % 80, br = r / 40, s = r % 40;
            const float* w2 = br ? ma_w2 : mu_w2;
            const float* b2 = br ? ma_b2 : mu_b2;
            float v = 0.f;
            if (s < 32) v = w2[d * 32 + s];
            else if (s < 34) v = b2[d * 2 + (s - 32)];
            ws[W2_OFF + idx] = v;
        }
        for (int idx = t; idx < 160; idx += 256) {
            float v = 0.f;
            if      (idx <  32) v = rd_w1[idx];
            else if (idx <  40) v = rd_b1[idx - 32];
            else if (idx <  72) v = rd_w2[idx - 40];
            else if (idx <  76) v = rd_b2[idx - 72];
            else if (idx < 108) v = rp_w1[idx - 76];
            else if (idx < 116) v = rp_b1[idx - 108];
            else if (idx < 148) v = rp_w2[idx - 116];
            else if (idx < 152) v = rp_b2[idx - 148];
            ws[RO_OFF + idx] = v;
        }
    }
    __threadfence();                       // writes visible at L2
    __syncthreads();                       // vmcnt(0) drain + barrier
    asm volatile("s_waitcnt lgkmcnt(0)\n\ts_dcache_inv" ::: "memory");  // K$ can't be stale

    const float* wsr = ws;

    const int b = blockIdx.x * 256 + threadIdx.x;

    float uf[M_][2];
    {
        const float4 u = ((const float4*)users)[b];
        uf[0][0] = u.x; uf[0][1] = u.y; uf[1][0] = u.z; uf[1][1] = u.w;
    }
    float af[N_][2];
    {
        const float4 p  = ((const float4*)power_init)[b];
        const float4 dl = ((const float4*)delta_init)[b];
        af[0][0] = p.x;  af[1][0] = p.y;  af[2][0] = p.z;  af[3][0] = p.w;
        af[0][1] = dl.x; af[1][1] = dl.y; af[2][1] = dl.z; af[3][1] = dl.w;
    }

#pragma unroll 1
    for (int d = 0; d < NB_; ++d) {
        const float* hpL  = wsr + HP_OFF  + d * 256;
        const float* w1uL = wsr + W1G_OFF + d * 1024;     // br=0; br=1 at +512
        const float* gbL  = wsr + SGB_OFF + d * 64;
        const float* w2L  = wsr + W2_OFF  + d * 80;

        // ---- node positions & edges (scalar) ----
        float da[N_], sd = 1e-6f;
#pragma unroll
        for (int n = 0; n < N_; ++n) { da[n] = fmaxf(af[n][1], 0.f); sd += da[n]; }
        const float rs = BMAX_v * frcp(sd);
        float xpos[N_];
        {
            float cum = 0.f;
#pragma unroll
            for (int n = 0; n < N_; ++n) {
                cum = fmaf(rs, da[n], cum);
                xpos[n] = cum - D_v + DMIN_v * (float)n;
            }
        }
        float edge[M_][N_];
#pragma unroll
        for (int m = 0; m < M_; ++m)
#pragma unroll
            for (int n = 0; n < N_; ++n) {
                const float dx = uf[m][0] - xpos[n], dy = uf[m][1];
                edge[m][n] = sqrtf(fmaf(dx, dx, dy * dy));
            }

        // ---- deferred-LN accumulators (f2 pairs over j) ----
        f2 Smu[M_][8], Sma[N_][8];
        f2 sxu2[M_], sxxu2[M_], sxa2[N_], sxxa2[N_];
#pragma unroll
        for (int m = 0; m < M_; ++m) {
            sxu2[m] = sp2(0.f); sxxu2[m] = sp2(0.f);
#pragma unroll
            for (int j = 0; j < 8; ++j) Smu[m][j] = sp2(0.f);
        }
#pragma unroll
        for (int n = 0; n < N_; ++n) {
            sxa2[n] = sp2(0.f); sxxa2[n] = sp2(0.f);
#pragma unroll
            for (int j = 0; j < 8; ++j) Sma[n][j] = sp2(0.f);
        }

        // ---- attention heads (rolled; weights via uniform s_load) ----
#pragma unroll 1
        for (int k = 0; k < NH_; ++k) {
            const f2* hp2 = (const f2*)(hpL + k * 32);
            const f2 wue[2] = {hp2[0],  hp2[1]};
            const f2 wuo[2] = {hp2[2],  hp2[3]};
            const f2 wae[2] = {hp2[4],  hp2[5]};
            const f2 wao[2] = {hp2[6],  hp2[7]};
            const f2 we2[2] = {hp2[8],  hp2[9]};
            const f2 av2[2] = {hp2[10], hp2[11]};
            const f2 wr0[2] = {hp2[12], hp2[13]};
            const f2 wr1[2] = {hp2[14], hp2[15]};

            // U/A projections: p indexes head-dim pairs (2p, 2p+1)
            f2 U2[M_][2], A2[N_][2];
#pragma unroll
            for (int p = 0; p < 2; ++p) {
#pragma unroll
                for (int m = 0; m < M_; ++m)
                    U2[m][p] = pfma(sp2(uf[m][0]), wue[p], sp2(uf[m][1]) * wuo[p]);
#pragma unroll
                for (int n = 0; n < N_; ++n)
                    A2[n][p] = pfma(sp2(af[n][0]), wae[p], sp2(af[n][1]) * wao[p]);
            }

            float alpha[M_][N_];
#pragma unroll
            for (int m = 0; m < M_; ++m) {
                float sc[N_];
#pragma unroll
                for (int n = 0; n < N_; ++n) {
                    const f2 e2 = sp2(edge[m][n]);
                    f2 s2 = sp2(0.f);
#pragma unroll
                    for (int p = 0; p < 2; ++p) {
                        f2 t = pfma(e2, we2[p], U2[m][p] + A2[n][p]);
                        t = pmax2(t, sp2(0.2f) * t);        // leaky_relu(0.2)
                        s2 = pfma(t, av2[p], s2);           // av has SCALE folded
                    }
                    sc[n] = s2.x + s2.y;
                }
                const float mx = fmaxf(fmaxf(sc[0], sc[1]), fmaxf(sc[2], sc[3]));
                float den = 0.f;
#pragma unroll
                for (int n = 0; n < N_; ++n) { sc[n] = __expf(sc[n] - mx); den += sc[n]; }
                const float rden = frcp(den);
#pragma unroll
                for (int n = 0; n < N_; ++n) alpha[m][n] = sc[n] * rden;
            }

            float eau[M_], ean[N_];
#pragma unroll
            for (int m = 0; m < M_; ++m) {
                float ea = 0.f;
#pragma unroll
                for (int n = 0; n < N_; ++n) ea = fmaf(edge[m][n], alpha[m][n], ea);
                eau[m] = ea;
            }
#pragma unroll
            for (int n = 0; n < N_; ++n)
                ean[n] = fmaf(edge[0][n], alpha[0][n], edge[1][n] * alpha[1][n]);

            // p covers head-dims (2p,2p+1) -> output cols k*4+2p, k*4+2p+1
#pragma unroll
            for (int p = 0; p < 2; ++p) {
                const int c0 = k * 4 + 2 * p;
                const f2* wc0u = (const f2*)(w1uL + c0 * 16);
                const f2* wc1u = wc0u + 8;
                const f2* wc0a = (const f2*)(w1uL + 512 + c0 * 16);
                const f2* wc1a = wc0a + 8;

                // --- user rows ---
                f2 xu[M_];
#pragma unroll
                for (int m = 0; m < M_; ++m) {
                    f2 uo = sp2(eau[m]) * we2[p];
#pragma unroll
                    for (int n = 0; n < N_; ++n) uo = pfma(sp2(alpha[m][n]), A2[n][p], uo);
                    f2 x2 = pfma(sp2(uf[m][0]), wr0[p], pfma(sp2(uf[m][1]), wr1[p], uo));
                    sxu2[m] = sxu2[m] + x2;
                    sxxu2[m] = pfma(x2, x2, sxxu2[m]);
                    xu[m] = x2;
                }
#pragma unroll
                for (int j = 0; j < 8; ++j) {
                    const f2 w0 = wc0u[j], w1v = wc1u[j];
#pragma unroll
                    for (int m = 0; m < M_; ++m) {
                        pk_fma_wlo(Smu[m][j], w0, xu[m]);   // += w(c0,j-pair)*x.lo
                        pk_fma_whi(Smu[m][j], w1v, xu[m]);  // += w(c0+1,j-pair)*x.hi
                    }
                }
                // --- node rows ---
                f2 xa[N_];
#pragma unroll
                for (int n = 0; n < N_; ++n) {
                    f2 x2 = pfma(sp2(alpha[0][n]), U2[0][p],
                            pfma(sp2(alpha[1][n]), U2[1][p], sp2(ean[n]) * we2[p]));
                    sxa2[n] = sxa2[n] + x2;
                    sxxa2[n] = pfma(x2, x2, sxxa2[n]);
                    xa[n] = x2;
                }
#pragma unroll
                for (int j = 0; j < 8; ++j) {
                    const f2 w0 = wc0a[j], w1v = wc1a[j];
#pragma unroll
                    for (int n = 0; n < N_; ++n) {
                        pk_fma_wlo(Sma[n][j], w0, xa[n]);
                        pk_fma_whi(Sma[n][j], w1v, xa[n]);
                    }
                }
            }
        } // heads

        // ---- MLPs with LN folded (f2 over j) ----
        const f2* Gmu2 = (const f2*)(gbL);
        const f2* Bmu2 = (const f2*)(gbL + 16);
        const f2* Gma2 = (const f2*)(gbL + 32);
        const f2* Bma2 = (const f2*)(gbL + 48);
        const f2* w2u0 = (const f2*)(w2L);
        const f2* w2u1 = (const f2*)(w2L + 16);
        const f2* w2a0 = (const f2*)(w2L + 40);
        const f2* w2a1 = (const f2*)(w2L + 56);

        float nuf[M_][2];
#pragma unroll
        for (int m = 0; m < M_; ++m) {
            const float sx = sxu2[m].x + sxu2[m].y;
            const float sxx = sxxu2[m].x + sxxu2[m].y;
            const float mu_ = sx * (1.0f / HID_);
            const float var = sxx * (1.0f / HID_) - mu_ * mu_;
            const float inv = rsqrtf(var + 1e-5f);
            f2 o0 = sp2(0.f), o1 = sp2(0.f);
#pragma unroll
            for (int j = 0; j < 8; ++j) {
                const f2 t = pfma(sp2(-mu_), Gmu2[j], Smu[m][j]);
                f2 pre = pfma(sp2(inv), t, Bmu2[j]);
                pre = pmax2(pre, sp2(0.f));
                o0 = pfma(pre, w2u0[j], o0);
                o1 = pfma(pre, w2u1[j], o1);
            }
            nuf[m][0] = o0.x + o0.y + w2L[32];
            nuf[m][1] = o1.x + o1.y + w2L[33];
        }
        float naf[N_][2];
#pragma unroll
        for (int n = 0; n < N_; ++n) {
            const float sx = sxa2[n].x + sxa2[n].y;
            const float sxx = sxxa2[n].x + sxxa2[n].y;
            const float mu_ = sx * (1.0f / HID_);
            const float var = sxx * (1.0f / HID_) - mu_ * mu_;
            const float inv = rsqrtf(var + 1e-5f);
            f2 o0 = sp2(0.f), o1 = sp2(0.f);
#pragma unroll
            for (int j = 0; j < 8; ++j) {
                const f2 t = pfma(sp2(-mu_), Gma2[j], Sma[n][j]);
                f2 pre = pfma(sp2(inv), t, Bma2[j]);
                pre = pmax2(pre, sp2(0.f));
                o0 = pfma(pre, w2a0[j], o0);
                o1 = pfma(pre, w2a1[j], o1);
            }
            naf[n][0] = o0.x + o0.y + w2L[72];
            naf[n][1] = o1.x + o1.y + w2L[73];
        }
#pragma unroll
        for (int m = 0; m < M_; ++m) { uf[m][0] = nuf[m][0]; uf[m][1] = nuf[m][1]; }
#pragma unroll
        for (int n = 0; n < N_; ++n) { af[n][0] = naf[n][0]; af[n][1] = naf[n][1]; }
    } // layers

    const float* ro = wsr + RO_OFF;

    // ---- delta readout ----
    float hid[8];
#pragma unroll
    for (int j = 0; j < 8; ++j) {
        float s = ro[32 + j];
#pragma unroll
        for (int n = 0; n < N_; ++n) s = fmaf(af[n][1], ro[j * 4 + n], s);
        hid[j] = fmaxf(s, 0.f);
    }
    float daux[N_];
    float sumd = 0.f;
#pragma unroll
    for (int n = 0; n < N_; ++n) {
        float s = ro[72 + n];
#pragma unroll
        for (int j = 0; j < 8; ++j) s = fmaf(hid[j], ro[40 + n * 8 + j], s);
        daux[n] = fmaxf(s, 0.001f);
        sumd += daux[n];
    }
    const float sdl = BMAX_v * frcp(sumd);
    float sdelta[N_], xf[N_];
    {
        float cum = 0.f;
#pragma unroll
        for (int n = 0; n < N_; ++n) {
            sdelta[n] = sdl * daux[n];
            cum += sdelta[n];
            xf[n] = cum + DMIN_v * (float)n - D_v * (float)(n + 1);
        }
    }

    // ---- power readout ----
    float hp_[8];
#pragma unroll
    for (int j = 0; j < 8; ++j) {
        float s = ro[108 + j];
#pragma unroll
        for (int n = 0; n < N_; ++n) s = fmaf(af[n][0], ro[76 + j * 4 + n], s);
        hp_[j] = fmaxf(s, 0.f);
    }
    float paux[N_];
    float sump = 1e-6f;
#pragma unroll
    for (int n = 0; n < N_; ++n) {
        float s = ro[148 + n];
#pragma unroll
        for (int j = 0; j < 8; ++j) s = fmaf(hp_[j], ro[116 + n * 8 + j], s);
        paux[n] = fmaxf(s, 0.001f);
        sump += paux[n];
    }
    const float pscale = PMAX_v * frcp(fmaxf(PMAX_v, sump));

    // ---- stores: scaled_power (B,4) | scaled_delta (B,4) | final_positions (B,4,3)
    float4 sp;
    sp.x = pscale * paux[0]; sp.y = pscale * paux[1];
    sp.z = pscale * paux[2]; sp.w = pscale * paux[3];
    ((float4*)out)[b] = sp;

    float4 sdv;
    sdv.x = sdelta[0]; sdv.y = sdelta[1]; sdv.z = sdelta[2]; sdv.w = sdelta[3];
    ((float4*)(out + (size_t)4 * BATCH))[b] = sdv;

    float* pos = out + (size_t)8 * BATCH + (size_t)b * 12;
    float4 p0, p1, p2;
    p0.x = xf[0]; p0.y = 0.f;   p0.z = HZ_v;  p0.w = xf[1];
    p1.x = 0.f;   p1.y = HZ_v;  p1.z = xf[2]; p1.w = 0.f;
    p2.x = HZ_v;  p2.y = xf[3]; p2.z = 0.f;   p2.w = HZ_v;
    ((float4*)pos)[0] = p0;
    ((float4*)pos)[1] = p1;
    ((float4*)pos)[2] = p2;
}

extern "C" void kernel_launch(void* const* d_in, const int* in_sizes, int n_in,
                              void* d_out, int out_size, void* d_ws, size_t ws_size,
                              hipStream_t stream) {
    const float* users      = (const float*)d_in[0];
    const float* delta_init = (const float*)d_in[1];
    const float* power_init = (const float*)d_in[2];
    const float* Wu    = (const float*)d_in[3];
    const float* Wa    = (const float*)d_in[4];
    const float* We    = (const float*)d_in[5];
    const float* av    = (const float*)d_in[6];
    const float* Wres  = (const float*)d_in[7];
    const float* lnu_g = (const float*)d_in[8];
    const float* lnu_b = (const float*)d_in[9];
    const float* lna_g = (const float*)d_in[10];
    const float* lna_b = (const float*)d_in[11];
    const float* mu_w1 = (const float*)d_in[12];
    const float* mu_b1 = (const float*)d_in[13];
    const float* mu_w2 = (const float*)d_in[14];
    const float* mu_b2 = (const float*)d_in[15];
    const float* ma_w1 = (const float*)d_in[16];
    const float* ma_b1 = (const float*)d_in[17];
    const float* ma_w2 = (const float*)d_in[18];
    const float* ma_b2 = (const float*)d_in[19];
    const float* rd_w1 = (const float*)d_in[20];
    const float* rd_b1 = (const float*)d_in[21];
    const float* rd_w2 = (const float*)d_in[22];
    const float* rd_b2 = (const float*)d_in[23];
    const float* rp_w1 = (const float*)d_in[24];
    const float* rp_b1 = (const float*)d_in[25];
    const float* rp_w2 = (const float*)d_in[26];
    const float* rp_b2 = (const float*)d_in[27];
    float* ws  = (float*)d_ws;
    float* out = (float*)d_out;

    hipLaunchKernelGGL(bgat_fwd, dim3(BATCH / 256), dim3(256), 0, stream,
                       users, delta_init, power_init, Wu, Wa, We, av, Wres,
                       lnu_g, lnu_b, lna_g, lna_b,
                       mu_w1, mu_b1, mu_w2, mu_b2,
                       ma_w1, ma_b1, ma_w2, ma_b2,
                       rd_w1, rd_b1, rd_w2, rd_b2,
                       rp_w1, rp_b1, rp_w2, rp_b2, ws, out);
}

// Round 11
// 287.257 us; speedup vs baseline: 1.9986x; 1.9986x over previous
//
#include <hip/hip_runtime.h>
#include <math.h>

// ---- Problem constants (fixed by the reference) ----
constexpr int BATCH = 262144;
constexpr int M_  = 2;
constexpr int N_  = 4;
constexpr int NB_ = 5;
constexpr int NH_ = 8;
constexpr int HD_ = 4;
constexpr int HID_ = 32;
constexpr float D_v    = 50.0f;
constexpr float HZ_v   = 5.0f;
constexpr float DMIN_v = 0.025f;
constexpr float PMAX_v = 1.0f;
constexpr float SCALE_v = 0.5f;                            // 1/sqrt(HD)
constexpr float BMAX_v  = 2.0f * D_v - (N_ - 1) * DMIN_v;  // 99.925
constexpr float LOG2E_v = 1.44269504088896340736f;

// ---- Packed-weight layout in d_ws (float offsets) ----
// HP  [5][8][32]     : per (layer,head), de-interleaved:
//                      wu_e4 | wu_o4 | wa_e4 | wa_o4 | we4 | av*SCALE*log2e 4 | wres0 4 | wres1 4
// W1G [5][2][32][16] : w1 transposed, LN gain folded ([d][br][col][j])
// SGB [5][4][16]     : per d: G_mu | B_mu | G_ma | B_ma (G=sum g*w1, B=sum b*w1+b1)
// W2  [5][2][40]     : w2 row0(16) | row1(16) | b2(2) | pad(6)
// RO  [160]          : rd_w1 rd_b1 rd_w2 rd_b2 rp_w1 rp_b1 rp_w2 rp_b2 pad
constexpr int HP_OFF  = 0;      // 1280
constexpr int W1G_OFF = 1280;   // 5120
constexpr int SGB_OFF = 6400;   // 320
constexpr int W2_OFF  = 6720;   // 400
constexpr int RO_OFF  = 7120;   // 160
constexpr int TOTF    = 7280;

typedef __attribute__((ext_vector_type(2))) float f2;

__device__ __forceinline__ float frcp(float x) { return __builtin_amdgcn_rcpf(x); }
__device__ __forceinline__ float fexp2(float x) { float d; asm("v_exp_f32 %0, %1" : "=v"(d) : "v"(x)); return d; }
__device__ __forceinline__ f2 sp2(float x) { return (f2){x, x}; }
__device__ __forceinline__ f2 pfma(f2 a, f2 b, f2 c) { return __builtin_elementwise_fma(a, b, c); }
__device__ __forceinline__ f2 pmax2(f2 a, f2 b) { return __builtin_elementwise_max(a, b); }

// ---- forced VOP3P for the dominant w1 matvec only (R8-verified).
// Tied accumulator ("+v") => no copy; op_sel broadcast => no v_mov.
__device__ __forceinline__ void pk_fma_wlo(f2& acc, f2 w, f2 x) {
    asm("v_pk_fma_f32 %0, %1, %2, %0 op_sel:[0,0,0] op_sel_hi:[1,0,1]"
        : "+v"(acc) : "s"(w), "v"(x));
}
__device__ __forceinline__ void pk_fma_whi(f2& acc, f2 w, f2 x) {
    asm("v_pk_fma_f32 %0, %1, %2, %0 op_sel:[0,1,0] op_sel_hi:[1,1,1]"
        : "+v"(acc) : "s"(w), "v"(x));
}

__global__ __launch_bounds__(256) void pack_weights(
    const float* __restrict__ Wu, const float* __restrict__ Wa, const float* __restrict__ We,
    const float* __restrict__ av, const float* __restrict__ Wres,
    const float* __restrict__ lnu_g, const float* __restrict__ lnu_b,
    const float* __restrict__ lna_g, const float* __restrict__ lna_b,
    const float* __restrict__ mu_w1, const float* __restrict__ mu_b1,
    const float* __restrict__ mu_w2, const float* __restrict__ mu_b2,
    const float* __restrict__ ma_w1, const float* __restrict__ ma_b1,
    const float* __restrict__ ma_w2, const float* __restrict__ ma_b2,
    const float* __restrict__ rd_w1, const float* __restrict__ rd_b1,
    const float* __restrict__ rd_w2, const float* __restrict__ rd_b2,
    const float* __restrict__ rp_w1, const float* __restrict__ rp_b1,
    const float* __restrict__ rp_w2, const float* __restrict__ rp_b2,
    float* __restrict__ ws)
{
    const int gid = blockIdx.x * 256 + threadIdx.x;
    if (gid >= TOTF) return;

    if (gid < HP_OFF + 1280) {
        const int idx = gid - HP_OFF;
        const int d = idx >> 8, r = idx & 255, k = r >> 5, s = r & 31;
        const int dk = d * 8 + k;
        float v;
        if      (s <  4) v = Wu[dk * 8 + 2 * s];
        else if (s <  8) v = Wu[dk * 8 + 2 * (s - 4) + 1];
        else if (s < 12) v = Wa[dk * 8 + 2 * (s - 8)];
        else if (s < 16) v = Wa[dk * 8 + 2 * (s - 12) + 1];
        else if (s < 20) v = We[dk * 4 + (s - 16)];
        else if (s < 24) v = av[dk * 4 + (s - 20)] * (SCALE_v * LOG2E_v);  // base-2 softmax fold (R9-verified)
        else if (s < 28) v = Wres[(d * 32 + k * 4 + (s - 24)) * 2 + 0];
        else             v = Wres[(d * 32 + k * 4 + (s - 28)) * 2 + 1];
        ws[gid] = v;
    } else if (gid < W1G_OFF + 5120) {
        const int idx = gid - W1G_OFF;
        const int d = idx >> 10, r = idx & 1023, br = r >> 9, r2 = r & 511;
        const int col = r2 >> 4, j = r2 & 15;
        const float* w1 = br ? ma_w1 : mu_w1;
        const float* g  = br ? lna_g : lnu_g;
        ws[gid] = w1[(d * 16 + j) * 32 + col] * g[d * 32 + col];
    } else if (gid < SGB_OFF + 320) {
        const int idx = gid - SGB_OFF;
        const int d = idx >> 6, r = idx & 63, q = r >> 4, j = r & 15;
        const int br = q >> 1, gb = q & 1;
        const float* w1 = (br ? ma_w1 : mu_w1) + (d * 16 + j) * 32;
        const float* gv = (br ? lna_g : lnu_g) + d * 32;
        const float* bv = (br ? lna_b : lnu_b) + d * 32;
        float acc = 0.f;
        if (gb == 0) { for (int i = 0; i < 32; ++i) acc = fmaf(gv[i], w1[i], acc); }
        else {
            for (int i = 0; i < 32; ++i) acc = fmaf(bv[i], w1[i], acc);
            acc += (br ? ma_b1 : mu_b1)[d * 16 + j];
        }
        ws[gid] = acc;
    } else if (gid < W2_OFF + 400) {
        const int idx = gid - W2_OFF;
        const int d = idx / 80, r = idx % 80, br = r / 40, s = r % 40;
        const float* w2 = br ? ma_w2 : mu_w2;
        const float* b2 = br ? ma_b2 : mu_b2;
        float v = 0.f;
        if (s < 32) v = w2[d * 32 + s];
        else if (s < 34) v = b2[d * 2 + (s - 32)];
        ws[gid] = v;
    } else {
        const int idx = gid - RO_OFF;
        float v = 0.f;
        if      (idx <  32) v = rd_w1[idx];
        else if (idx <  40) v = rd_b1[idx - 32];
        else if (idx <  72) v = rd_w2[idx - 40];
        else if (idx <  76) v = rd_b2[idx - 72];
        else if (idx < 108) v = rp_w1[idx - 76];
        else if (idx < 116) v = rp_b1[idx - 108];
        else if (idx < 148) v = rp_w2[idx - 116];
        else if (idx < 152) v = rp_b2[idx - 148];
        ws[gid] = v;
    }
}

// One thread = one batch element. Weights via wave-uniform s_load (zero LDS,
// proven R5+). Body = R8 (best, 205.6us) + base-2 softmax (av carries
// SCALE*log2e; exp -> v_exp_f32 directly, one mul shorter dep chain).
__global__ __launch_bounds__(256) void bgat_fwd(
    const float* __restrict__ ws,
    const float* __restrict__ users, const float* __restrict__ delta_init,
    const float* __restrict__ power_init, float* __restrict__ out)
{
    const int b = blockIdx.x * 256 + threadIdx.x;

    float uf[M_][2];
    {
        const float4 u = ((const float4*)users)[b];
        uf[0][0] = u.x; uf[0][1] = u.y; uf[1][0] = u.z; uf[1][1] = u.w;
    }
    float af[N_][2];
    {
        const float4 p  = ((const float4*)power_init)[b];
        const float4 dl = ((const float4*)delta_init)[b];
        af[0][0] = p.x;  af[1][0] = p.y;  af[2][0] = p.z;  af[3][0] = p.w;
        af[0][1] = dl.x; af[1][1] = dl.y; af[2][1] = dl.z; af[3][1] = dl.w;
    }

#pragma unroll 1
    for (int d = 0; d < NB_; ++d) {
        const float* hpL  = ws + HP_OFF  + d * 256;
        const float* w1uL = ws + W1G_OFF + d * 1024;     // br=0; br=1 at +512
        const float* gbL  = ws + SGB_OFF + d * 64;
        const float* w2L  = ws + W2_OFF  + d * 80;

        // ---- node positions & edges (scalar) ----
        float da[N_], sd = 1e-6f;
#pragma unroll
        for (int n = 0; n < N_; ++n) { da[n] = fmaxf(af[n][1], 0.f); sd += da[n]; }
        const float rs = BMAX_v * frcp(sd);
        float xpos[N_];
        {
            float cum = 0.f;
#pragma unroll
            for (int n = 0; n < N_; ++n) {
                cum = fmaf(rs, da[n], cum);
                xpos[n] = cum - D_v + DMIN_v * (float)n;
            }
        }
        float edge[M_][N_];
#pragma unroll
        for (int m = 0; m < M_; ++m)
#pragma unroll
            for (int n = 0; n < N_; ++n) {
                const float dx = uf[m][0] - xpos[n], dy = uf[m][1];
                edge[m][n] = sqrtf(fmaf(dx, dx, dy * dy));
            }

        // ---- deferred-LN accumulators (f2 pairs over j) ----
        f2 Smu[M_][8], Sma[N_][8];
        f2 sxu2[M_], sxxu2[M_], sxa2[N_], sxxa2[N_];
#pragma unroll
        for (int m = 0; m < M_; ++m) {
            sxu2[m] = sp2(0.f); sxxu2[m] = sp2(0.f);
#pragma unroll
            for (int j = 0; j < 8; ++j) Smu[m][j] = sp2(0.f);
        }
#pragma unroll
        for (int n = 0; n < N_; ++n) {
            sxa2[n] = sp2(0.f); sxxa2[n] = sp2(0.f);
#pragma unroll
            for (int j = 0; j < 8; ++j) Sma[n][j] = sp2(0.f);
        }

        // ---- attention heads (rolled; weights via uniform s_load) ----
#pragma unroll 1
        for (int k = 0; k < NH_; ++k) {
            const f2* hp2 = (const f2*)(hpL + k * 32);
            const f2 wue[2] = {hp2[0],  hp2[1]};
            const f2 wuo[2] = {hp2[2],  hp2[3]};
            const f2 wae[2] = {hp2[4],  hp2[5]};
            const f2 wao[2] = {hp2[6],  hp2[7]};
            const f2 we2[2] = {hp2[8],  hp2[9]};
            const f2 av2[2] = {hp2[10], hp2[11]};   // av*SCALE*log2e
            const f2 wr0[2] = {hp2[12], hp2[13]};
            const f2 wr1[2] = {hp2[14], hp2[15]};

            // U/A projections: p indexes head-dim pairs (2p, 2p+1)
            f2 U2[M_][2], A2[N_][2];
#pragma unroll
            for (int p = 0; p < 2; ++p) {
#pragma unroll
                for (int m = 0; m < M_; ++m)
                    U2[m][p] = pfma(sp2(uf[m][0]), wue[p], sp2(uf[m][1]) * wuo[p]);
#pragma unroll
                for (int n = 0; n < N_; ++n)
                    A2[n][p] = pfma(sp2(af[n][0]), wae[p], sp2(af[n][1]) * wao[p]);
            }

            float alpha[M_][N_];
#pragma unroll
            for (int m = 0; m < M_; ++m) {
                float sc[N_];
#pragma unroll
                for (int n = 0; n < N_; ++n) {
                    const f2 e2 = sp2(edge[m][n]);
                    f2 s2 = sp2(0.f);
#pragma unroll
                    for (int p = 0; p < 2; ++p) {
                        f2 t = pfma(e2, we2[p], U2[m][p] + A2[n][p]);
                        t = pmax2(t, sp2(0.2f) * t);        // leaky_relu(0.2)
                        s2 = pfma(t, av2[p], s2);           // av has SCALE*log2e folded
                    }
                    sc[n] = s2.x + s2.y;
                }
                const float mx = fmaxf(fmaxf(sc[0], sc[1]), fmaxf(sc[2], sc[3]));
                float den = 0.f;
#pragma unroll
                for (int n = 0; n < N_; ++n) { sc[n] = fexp2(sc[n] - mx); den += sc[n]; }
                const float rden = frcp(den);
#pragma unroll
                for (int n = 0; n < N_; ++n) alpha[m][n] = sc[n] * rden;
            }

            float eau[M_], ean[N_];
#pragma unroll
            for (int m = 0; m < M_; ++m) {
                float ea = 0.f;
#pragma unroll
                for (int n = 0; n < N_; ++n) ea = fmaf(edge[m][n], alpha[m][n], ea);
                eau[m] = ea;
            }
#pragma unroll
            for (int n = 0; n < N_; ++n)
                ean[n] = fmaf(edge[0][n], alpha[0][n], edge[1][n] * alpha[1][n]);

            // p covers head-dims (2p,2p+1) -> output cols k*4+2p, k*4+2p+1
#pragma unroll
            for (int p = 0; p < 2; ++p) {
                const int c0 = k * 4 + 2 * p;
                const f2* wc0u = (const f2*)(w1uL + c0 * 16);
                const f2* wc1u = wc0u + 8;
                const f2* wc0a = (const f2*)(w1uL + 512 + c0 * 16);
                const f2* wc1a = wc0a + 8;

                // --- user rows ---
                f2 xu[M_];
#pragma unroll
                for (int m = 0; m < M_; ++m) {
                    f2 uo = sp2(eau[m]) * we2[p];
#pragma unroll
                    for (int n = 0; n < N_; ++n) uo = pfma(sp2(alpha[m][n]), A2[n][p], uo);
                    f2 x2 = pfma(sp2(uf[m][0]), wr0[p], pfma(sp2(uf[m][1]), wr1[p], uo));
                    sxu2[m] = sxu2[m] + x2;
                    sxxu2[m] = pfma(x2, x2, sxxu2[m]);
                    xu[m] = x2;
                }
#pragma unroll
                for (int j = 0; j < 8; ++j) {
                    const f2 w0 = wc0u[j], w1v = wc1u[j];
#pragma unroll
                    for (int m = 0; m < M_; ++m) {
                        pk_fma_wlo(Smu[m][j], w0, xu[m]);   // += w(c0,j-pair)*x.lo
                        pk_fma_whi(Smu[m][j], w1v, xu[m]);  // += w(c0+1,j-pair)*x.hi
                    }
                }
                // --- node rows ---
                f2 xa[N_];
#pragma unroll
                for (int n = 0; n < N_; ++n) {
                    f2 x2 = pfma(sp2(alpha[0][n]), U2[0][p],
                            pfma(sp2(alpha[1][n]), U2[1][p], sp2(ean[n]) * we2[p]));
                    sxa2[n] = sxa2[n] + x2;
                    sxxa2[n] = pfma(x2, x2, sxxa2[n]);
                    xa[n] = x2;
                }
#pragma unroll
                for (int j = 0; j < 8; ++j) {
                    const f2 w0 = wc0a[j], w1v = wc1a[j];
#pragma unroll
                    for (int n = 0; n < N_; ++n) {
                        pk_fma_wlo(Sma[n][j], w0, xa[n]);
                        pk_fma_whi(Sma[n][j], w1v, xa[n]);
                    }
                }
            }
        } // heads

        // ---- MLPs with LN folded (f2 over j) ----
        const f2* Gmu2 = (const f2*)(gbL);
        const f2* Bmu2 = (const f2*)(gbL + 16);
        const f2* Gma2 = (const f2*)(gbL + 32);
        const f2* Bma2 = (const f2*)(gbL + 48);
        const f2* w2u0 = (const f2*)(w2L);
        const f2* w2u1 = (const f2*)(w2L + 16);
        const f2* w2a0 = (const f2*)(w2L + 40);
        const f2* w2a1 = (const f2*)(w2L + 56);

        float nuf[M_][2];
#pragma unroll
        for (int m = 0; m < M_; ++m) {
            const float sx = sxu2[m].x + sxu2[m].y;
            const float sxx = sxxu2[m].x + sxxu2[m].y;
            const float mu_ = sx * (1.0f / HID_);
            const float var = sxx * (1.0f / HID_) - mu_ * mu_;
            const float inv = rsqrtf(var + 1e-5f);
            f2 o0 = sp2(0.f), o1 = sp2(0.f);
#pragma unroll
            for (int j = 0; j < 8; ++j) {
                const f2 t = pfma(sp2(-mu_), Gmu2[j], Smu[m][j]);
                f2 pre = pfma(sp2(inv), t, Bmu2[j]);
                pre = pmax2(pre, sp2(0.f));
                o0 = pfma(pre, w2u0[j], o0);
                o1 = pfma(pre, w2u1[j], o1);
            }
            nuf[m][0] = o0.x + o0.y + w2L[32];
            nuf[m][1] = o1.x + o1.y + w2L[33];
        }
        float naf[N_][2];
#pragma unroll
        for (int n = 0; n < N_; ++n) {
            const float sx = sxa2[n].x + sxa2[n].y;
            const float sxx = sxxa2[n].x + sxxa2[n].y;
            const float mu_ = sx * (1.0f / HID_);
            const float var = sxx * (1.0f / HID_) - mu_ * mu_;
            const float inv = rsqrtf(var + 1e-5f);
            f2 o0 = sp2(0.f), o1 = sp2(0.f);
#pragma unroll
            for (int j = 0; j < 8; ++j) {
                const f2 t = pfma(sp2(-mu_), Gma2[j], Sma[n][j]);
                f2 pre = pfma(sp2(inv), t, Bma2[j]);
                pre = pmax2(pre, sp2(0.f));
                o0 = pfma(pre, w2a0[j], o0);
                o1 = pfma(pre, w2a1[j], o1);
            }
            naf[n][0] = o0.x + o0.y + w2L[72];
            naf[n][1] = o1.x + o1.y + w2L[73];
        }
#pragma unroll
        for (int m = 0; m < M_; ++m) { uf[m][0] = nuf[m][0]; uf[m][1] = nuf[m][1]; }
#pragma unroll
        for (int n = 0; n < N_; ++n) { af[n][0] = naf[n][0]; af[n][1] = naf[n][1]; }
    } // layers

    const float* ro = ws + RO_OFF;

    // ---- delta readout ----
    float hid[8];
#pragma unroll
    for (int j = 0; j < 8; ++j) {
        float s = ro[32 + j];
#pragma unroll
        for (int n = 0; n < N_; ++n) s = fmaf(af[n][1], ro[j * 4 + n], s);
        hid[j] = fmaxf(s, 0.f);
    }
    float daux[N_];
    float sumd = 0.f;
#pragma unroll
    for (int n = 0; n < N_; ++n) {
        float s = ro[72 + n];
#pragma unroll
        for (int j = 0; j < 8; ++j) s = fmaf(hid[j], ro[40 + n * 8 + j], s);
        daux[n] = fmaxf(s, 0.001f);
        sumd += daux[n];
    }
    const float sdl = BMAX_v * frcp(sumd);
    float sdelta[N_], xf[N_];
    {
        float cum = 0.f;
#pragma unroll
        for (int n = 0; n < N_; ++n) {
            sdelta[n] = sdl * daux[n];
            cum += sdelta[n];
            xf[n] = cum + DMIN_v * (float)n - D_v * (float)(n + 1);
        }
    }

    // ---- power readout ----
    float hp_[8];
#pragma unroll
    for (int j = 0; j < 8; ++j) {
        float s = ro[108 + j];
#pragma unroll
        for (int n = 0; n < N_; ++n) s = fmaf(af[n][0], ro[76 + j * 4 + n], s);
        hp_[j] = fmaxf(s, 0.f);
    }
    float paux[N_];
    float sump = 1e-6f;
#pragma unroll
    for (int n = 0; n < N_; ++n) {
        float s = ro[148 + n];
#pragma unroll
        for (int j = 0; j < 8; ++j) s = fmaf(hp_[j], ro[116 + n * 8 + j], s);
        paux[n] = fmaxf(s, 0.001f);
        sump += paux[n];
    }
    const float pscale = PMAX_v * frcp(fmaxf(PMAX_v, sump));

    // ---- stores: scaled_power (B,4) | scaled_delta (B,4) | final_positions (B,4,3)
    float4 sp;
    sp.x = pscale * paux[0]; sp.y = pscale * paux[1];
    sp.z = pscale * paux[2]; sp.w = pscale * paux[3];
    ((float4*)out)[b] = sp;

    float4 sdv;
    sdv.x = sdelta[0]; sdv.y = sdelta[1]; sdv.z = sdelta[2]; sdv.w = sdelta[3];
    ((float4*)(out + (size_t)4 * BATCH))[b] = sdv;

    float* pos = out + (size_t)8 * BATCH + (size_t)b * 12;
    float4 p0, p1, p2;
    p0.x = xf[0]; p0.y = 0.f;   p0.z = HZ_v;  p0.w = xf[1];
    p1.x = 0.f;   p1.y = HZ_v;  p1.z = xf[2]; p1.w = 0.f;
    p2.x = HZ_v;  p2.y = xf[3]; p2.z = 0.f;   p2.w = HZ_v;
    ((float4*)pos)[0] = p0;
    ((float4*)pos)[1] = p1;
    ((float4*)pos)[2] = p2;
}

extern "C" void kernel_launch(void* const* d_in, const int* in_sizes, int n_in,
                              void* d_out, int out_size, void* d_ws, size_t ws_size,
                              hipStream_t stream) {
    const float* users      = (const float*)d_in[0];
    const float* delta_init = (const float*)d_in[1];
    const float* power_init = (const float*)d_in[2];
    const float* Wu    = (const float*)d_in[3];
    const float* Wa    = (const float*)d_in[4];
    const float* We    = (const float*)d_in[5];
    const float* av    = (const float*)d_in[6];
    const float* Wres  = (const float*)d_in[7];
    const float* lnu_g = (const float*)d_in[8];
    const float* lnu_b = (const float*)d_in[9];
    const float* lna_g = (const float*)d_in[10];
    const float* lna_b = (const float*)d_in[11];
    const float* mu_w1 = (const float*)d_in[12];
    const float* mu_b1 = (const float*)d_in[13];
    const float* mu_w2 = (const float*)d_in[14];
    const float* mu_b2 = (const float*)d_in[15];
    const float* ma_w1 = (const float*)d_in[16];
    const float* ma_b1 = (const float*)d_in[17];
    const float* ma_w2 = (const float*)d_in[18];
    const float* ma_b2 = (const float*)d_in[19];
    const float* rd_w1 = (const float*)d_in[20];
    const float* rd_b1 = (const float*)d_in[21];
    const float* rd_w2 = (const float*)d_in[22];
    const float* rd_b2 = (const float*)d_in[23];
    const float* rp_w1 = (const float*)d_in[24];
    const float* rp_b1 = (const float*)d_in[25];
    const float* rp_w2 = (const float*)d_in[26];
    const float* rp_b2 = (const float*)d_in[27];
    float* ws  = (float*)d_ws;
    float* out = (float*)d_out;

    hipLaunchKernelGGL(pack_weights, dim3((TOTF + 255) / 256), dim3(256), 0, stream,
                       Wu, Wa, We, av, Wres, lnu_g, lnu_b, lna_g, lna_b,
                       mu_w1, mu_b1, mu_w2, mu_b2, ma_w1, ma_b1, ma_w2, ma_b2,
                       rd_w1, rd_b1, rd_w2, rd_b2, rp_w1, rp_b1, rp_w2, rp_b2, ws);

    hipLaunchKernelGGL(bgat_fwd, dim3(BATCH / 256), dim3(256), 0, stream,
                       ws, users, delta_init, power_init, out);
}